// Round 1
// baseline (281.957 us; speedup 1.0000x reference)
//
#include <hip/hip_runtime.h>
#include <cstdint>
#include <cstddef>

#define BB 4
#define HCC 32
#define WCC 32
#define KCC 1024
#define NCC (HCC*WCC)   /* 1024 */
#define HFF 128
#define WFF 128
#define KFF 256
#define DCC 4
#define NCHUNK 8
#define MCHUNK 128

// ---------------- squared row norms (one wave per row) ----------------
__global__ __launch_bounds__(256) void norms_kernel(
    const float* __restrict__ x0, const float* __restrict__ x1,
    float* __restrict__ o0, float* __restrict__ o1, int rows, int K4) {
  const float* __restrict__ x = blockIdx.y ? x1 : x0;
  float* __restrict__ o = blockIdx.y ? o1 : o0;
  int wave = threadIdx.x >> 6, lane = threadIdx.x & 63;
  int row = blockIdx.x * 4 + wave;
  if (row >= rows) return;
  const float4* __restrict__ p = (const float4*)(x + (size_t)row * ((size_t)K4 * 4));
  float s = 0.f;
  for (int idx = lane; idx < K4; idx += 64) {
    float4 v = p[idx];
    s += v.x*v.x + v.y*v.y + v.z*v.z + v.w*v.w;
  }
  #pragma unroll
  for (int m = 32; m; m >>= 1) s += __shfl_xor(s, m, 64);
  if (lane == 0) o[row] = s;
}

// ---------------- coarse: tiled GEMM + per-chunk argmin ----------------
// grid (NCHUNK=8, 16 n-tiles, B). block 256. tile: 64 queries x 128 cands.
__global__ __launch_bounds__(256) void coarse_kernel(
    const float* __restrict__ f1, const float* __restrict__ fk,
    const float* __restrict__ na, const float* __restrict__ nq,
    float* __restrict__ pval, int* __restrict__ pidx) {
  __shared__ float As[64][36];
  __shared__ float Bs0[32][68];
  __shared__ float Bs1[32][68];

  const int t = threadIdx.x;
  const int chunk = blockIdx.x;
  const int n0 = blockIdx.y * 64;
  const int b = blockIdx.z;
  const int m0 = chunk * MCHUNK;

  const float* __restrict__ Aby = fk + (size_t)b * NCC * KCC;  // queries
  const float* __restrict__ Bby = f1 + (size_t)b * NCC * KCC;  // candidates

  const int lr = t >> 2;          // 0..63
  const int lq = (t & 3) * 4;     // 0,4,8,12

  float acc0[4][4], acc1[4][4];
  #pragma unroll
  for (int i2 = 0; i2 < 4; ++i2)
    #pragma unroll
    for (int j2 = 0; j2 < 4; ++j2) { acc0[i2][j2] = 0.f; acc1[i2][j2] = 0.f; }

  const int tr = t >> 4, tc = t & 15;

  for (int k0 = 0; k0 < KCC; k0 += 32) {
    // A tile 64x32 (row-major, pad 36)
    {
      const float* src = Aby + (size_t)(n0 + lr) * KCC + k0 + lq;
      float4 v0 = *(const float4*)src;
      float4 v1 = *(const float4*)(src + 16);
      *(float4*)&As[lr][lq] = v0;
      *(float4*)&As[lr][lq + 16] = v1;
    }
    // B tiles 2 x (64 cands x 32 k), stored transposed [k][col] pad 68
    {
      const float* src = Bby + (size_t)(m0 + lr) * KCC + k0 + lq;
      float4 v0 = *(const float4*)src;
      float4 v1 = *(const float4*)(src + 16);
      Bs0[lq+0][lr] = v0.x; Bs0[lq+1][lr] = v0.y; Bs0[lq+2][lr] = v0.z; Bs0[lq+3][lr] = v0.w;
      Bs0[lq+16][lr] = v1.x; Bs0[lq+17][lr] = v1.y; Bs0[lq+18][lr] = v1.z; Bs0[lq+19][lr] = v1.w;
      const float* src1 = Bby + (size_t)(m0 + 64 + lr) * KCC + k0 + lq;
      float4 w0 = *(const float4*)src1;
      float4 w1 = *(const float4*)(src1 + 16);
      Bs1[lq+0][lr] = w0.x; Bs1[lq+1][lr] = w0.y; Bs1[lq+2][lr] = w0.z; Bs1[lq+3][lr] = w0.w;
      Bs1[lq+16][lr] = w1.x; Bs1[lq+17][lr] = w1.y; Bs1[lq+18][lr] = w1.z; Bs1[lq+19][lr] = w1.w;
    }
    __syncthreads();

    #pragma unroll
    for (int k4 = 0; k4 < 8; ++k4) {
      float ak[4][4];
      #pragma unroll
      for (int i2 = 0; i2 < 4; ++i2) {
        float4 a4 = *(const float4*)&As[tr*4 + i2][k4*4];
        ak[i2][0] = a4.x; ak[i2][1] = a4.y; ak[i2][2] = a4.z; ak[i2][3] = a4.w;
      }
      #pragma unroll
      for (int kk = 0; kk < 4; ++kk) {
        float4 b0 = *(const float4*)&Bs0[k4*4 + kk][tc*4];
        float4 b1 = *(const float4*)&Bs1[k4*4 + kk][tc*4];
        #pragma unroll
        for (int i2 = 0; i2 < 4; ++i2) {
          float av = ak[i2][kk];
          acc0[i2][0] = fmaf(av, b0.x, acc0[i2][0]);
          acc0[i2][1] = fmaf(av, b0.y, acc0[i2][1]);
          acc0[i2][2] = fmaf(av, b0.z, acc0[i2][2]);
          acc0[i2][3] = fmaf(av, b0.w, acc0[i2][3]);
          acc1[i2][0] = fmaf(av, b1.x, acc1[i2][0]);
          acc1[i2][1] = fmaf(av, b1.y, acc1[i2][1]);
          acc1[i2][2] = fmaf(av, b1.z, acc1[i2][2]);
          acc1[i2][3] = fmaf(av, b1.w, acc1[i2][3]);
        }
      }
    }
    __syncthreads();
  }

  // epilogue: dist = (q2 + a2) - 2*dot, argmin with first-index ties
  float q2[4];
  #pragma unroll
  for (int i2 = 0; i2 < 4; ++i2) q2[i2] = nq[b*NCC + n0 + tr*4 + i2];

  #pragma unroll
  for (int i2 = 0; i2 < 4; ++i2) {
    float bv = 3.0e38f; int bi = 0;
    #pragma unroll
    for (int j2 = 0; j2 < 4; ++j2) {
      int m = m0 + tc*4 + j2;
      float d = (q2[i2] + na[b*NCC + m]) - 2.0f * acc0[i2][j2];
      if (d < bv) { bv = d; bi = m; }
    }
    #pragma unroll
    for (int j2 = 0; j2 < 4; ++j2) {
      int m = m0 + 64 + tc*4 + j2;
      float d = (q2[i2] + na[b*NCC + m]) - 2.0f * acc1[i2][j2];
      if (d < bv) { bv = d; bi = m; }
    }
    // reduce across the 16 tc lanes (lane-contiguous group)
    #pragma unroll
    for (int m = 1; m < 16; m <<= 1) {
      float ov = __shfl_xor(bv, m, 64);
      int oi = __shfl_xor(bi, m, 64);
      if (ov < bv || (ov == bv && oi < bi)) { bv = ov; bi = oi; }
    }
    if (tc == 0) {
      int n = n0 + tr*4 + i2;
      pval[((size_t)b*NCC + n)*NCHUNK + chunk] = bv;
      pidx[((size_t)b*NCC + n)*NCHUNK + chunk] = bi;
    }
  }
}

// ---------------- coarse: combine chunk partials ----------------
__global__ __launch_bounds__(256) void coarse_reduce_kernel(
    const float* __restrict__ pval, const int* __restrict__ pidx,
    int* __restrict__ out) {
  int g = blockIdx.x * 256 + threadIdx.x;
  if (g >= BB * NCC) return;
  float bv = pval[(size_t)g * NCHUNK];
  int bi = pidx[(size_t)g * NCHUNK];
  #pragma unroll
  for (int c = 1; c < NCHUNK; ++c) {
    float v = pval[(size_t)g * NCHUNK + c];
    int ix = pidx[(size_t)g * NCHUNK + c];
    if (v < bv) { bv = v; bi = ix; }   // idx ascending with chunk -> first-min kept
  }
  out[(size_t)g*2]     = bi >> 5;   // // WC
  out[(size_t)g*2 + 1] = bi & 31;   // % WC
}

// ---------------- fine: per-cell 16x144 match ----------------
// grid (WC=32, HC=32, B). block 192 = 3 waves. thread tile 4p x 3n.
__global__ __launch_bounds__(192) void fine_kernel(
    const float* __restrict__ f1, const float* __restrict__ fkf,
    const float* __restrict__ na, const float* __restrict__ nq,
    const int* __restrict__ coarse, int* __restrict__ outf) {
  __shared__ float qs[16][260];
  __shared__ float q2s[16];
  __shared__ int cbr[9], cbc[9];
  __shared__ float rbv[16][48];
  __shared__ int rbi[16][48];

  const int t = threadIdx.x;
  const int j = blockIdx.x, i = blockIdx.y, b = blockIdx.z;

  if (t < 9) {
    int di = t / 3 - 1, dj = t % 3 - 1;
    int y = min(max(i + di, 0), HCC - 1);
    int x = min(max(j + dj, 0), WCC - 1);
    int base = ((b*HCC + y)*WCC + x) * 2;
    cbr[t] = coarse[base];
    cbc[t] = coarse[base + 1];
  }
  if (t < 16) {
    int fr = i*DCC + (t >> 2), fc = j*DCC + (t & 3);
    q2s[t] = nq[((size_t)b*HFF + fr)*WFF + fc];
  }
  // stage 16 query rows (256 floats each) into LDS
  for (int idx = t; idx < 16 * 64; idx += 192) {
    int p = idx >> 6, c4 = idx & 63;
    int fr = i*DCC + (p >> 2), fc = j*DCC + (p & 3);
    float4 v = *(const float4*)(fkf + (((size_t)b*HFF + fr)*WFF + fc)*KFF + (size_t)c4*4);
    *(float4*)&qs[p][c4*4] = v;
  }
  __syncthreads();

  const int tp = t & 3;        // p-tile (rows tp*4..tp*4+3)
  const int tn = t >> 2;       // 0..47, candidates tn*3..tn*3+2
  const float* cp0; const float* cp1; const float* cp2;
  float c20, c21, c22;
  {
    int c = tn * 3;
    int n9, s, row, col;
    n9 = (c+0) >> 4; s = (c+0) & 15;
    row = cbr[n9]*DCC + (s >> 2); col = cbc[n9]*DCC + (s & 3);
    cp0 = f1 + (((size_t)b*HFF + row)*WFF + col)*KFF;
    c20 = na[((size_t)b*HFF + row)*WFF + col];
    n9 = (c+1) >> 4; s = (c+1) & 15;
    row = cbr[n9]*DCC + (s >> 2); col = cbc[n9]*DCC + (s & 3);
    cp1 = f1 + (((size_t)b*HFF + row)*WFF + col)*KFF;
    c21 = na[((size_t)b*HFF + row)*WFF + col];
    n9 = (c+2) >> 4; s = (c+2) & 15;
    row = cbr[n9]*DCC + (s >> 2); col = cbc[n9]*DCC + (s & 3);
    cp2 = f1 + (((size_t)b*HFF + row)*WFF + col)*KFF;
    c22 = na[((size_t)b*HFF + row)*WFF + col];
  }

  float acc[4][3];
  #pragma unroll
  for (int ii = 0; ii < 4; ++ii) { acc[ii][0] = 0.f; acc[ii][1] = 0.f; acc[ii][2] = 0.f; }

  #pragma unroll 4
  for (int k4 = 0; k4 < 64; ++k4) {
    float4 cv0 = *(const float4*)(cp0 + (size_t)k4*4);
    float4 cv1 = *(const float4*)(cp1 + (size_t)k4*4);
    float4 cv2 = *(const float4*)(cp2 + (size_t)k4*4);
    #pragma unroll
    for (int ii = 0; ii < 4; ++ii) {
      float4 qv = *(const float4*)&qs[tp*4 + ii][k4*4];
      acc[ii][0] = fmaf(qv.x, cv0.x, acc[ii][0]);
      acc[ii][0] = fmaf(qv.y, cv0.y, acc[ii][0]);
      acc[ii][0] = fmaf(qv.z, cv0.z, acc[ii][0]);
      acc[ii][0] = fmaf(qv.w, cv0.w, acc[ii][0]);
      acc[ii][1] = fmaf(qv.x, cv1.x, acc[ii][1]);
      acc[ii][1] = fmaf(qv.y, cv1.y, acc[ii][1]);
      acc[ii][1] = fmaf(qv.z, cv1.z, acc[ii][1]);
      acc[ii][1] = fmaf(qv.w, cv1.w, acc[ii][1]);
      acc[ii][2] = fmaf(qv.x, cv2.x, acc[ii][2]);
      acc[ii][2] = fmaf(qv.y, cv2.y, acc[ii][2]);
      acc[ii][2] = fmaf(qv.z, cv2.z, acc[ii][2]);
      acc[ii][2] = fmaf(qv.w, cv2.w, acc[ii][2]);
    }
  }

  #pragma unroll
  for (int ii = 0; ii < 4; ++ii) {
    float q2 = q2s[tp*4 + ii];
    float bv = 3.0e38f; int bi = 0;
    float d0 = (q2 + c20) - 2.0f * acc[ii][0];
    float d1 = (q2 + c21) - 2.0f * acc[ii][1];
    float d2 = (q2 + c22) - 2.0f * acc[ii][2];
    if (d0 < bv) { bv = d0; bi = tn*3 + 0; }
    if (d1 < bv) { bv = d1; bi = tn*3 + 1; }
    if (d2 < bv) { bv = d2; bi = tn*3 + 2; }
    rbv[tp*4 + ii][tn] = bv;
    rbi[tp*4 + ii][tn] = bi;
  }
  __syncthreads();

  if (t < 16) {
    float v = rbv[t][0]; int ix = rbi[t][0];
    for (int s2 = 1; s2 < 48; ++s2) {
      float ov = rbv[t][s2];
      if (ov < v) { v = ov; ix = rbi[t][s2]; }   // ascending idx -> first-min
    }
    int n9 = ix >> 4, s3 = ix & 15;
    int br = cbr[n9]*DCC + (s3 >> 2);
    int bc = cbc[n9]*DCC + (s3 & 3);
    int fr = i*DCC + (t >> 2), fc = j*DCC + (t & 3);
    size_t ob = (((size_t)b*HFF + fr)*WFF + fc) * 2;
    outf[ob]     = br;
    outf[ob + 1] = bc;
  }
}

extern "C" void kernel_launch(void* const* d_in, const int* in_sizes, int n_in,
                              void* d_out, int out_size, void* d_ws, size_t ws_size,
                              hipStream_t stream) {
  (void)in_sizes; (void)n_in; (void)out_size; (void)ws_size;
  const float* f1c = (const float*)d_in[0];
  const float* fkc = (const float*)d_in[1];
  const float* f1f = (const float*)d_in[2];
  const float* fkf = (const float*)d_in[3];
  int* out = (int*)d_out;

  float* ws = (float*)d_ws;
  float* nq_c = ws;                        // 4096
  float* na_c = ws + 4096;                 // 4096
  float* nq_f = ws + 8192;                 // 65536
  float* na_f = ws + 8192 + 65536;         // 65536
  float* pval = ws + 8192 + 131072;        // 32768
  int*   pidx = (int*)(ws + 8192 + 131072 + 32768);

  // squared norms: coarse (k=1024) and fine (k=256)
  norms_kernel<<<dim3(BB*NCC/4, 2), 256, 0, stream>>>(fkc, f1c, nq_c, na_c, BB*NCC, KCC/4);
  norms_kernel<<<dim3(BB*HFF*WFF/4, 2), 256, 0, stream>>>(fkf, f1f, nq_f, na_f, BB*HFF*WFF, KFF/4);

  // coarse match
  coarse_kernel<<<dim3(NCHUNK, NCC/64, BB), 256, 0, stream>>>(f1c, fkc, na_c, nq_c, pval, pidx);
  coarse_reduce_kernel<<<dim3((BB*NCC + 255)/256), 256, 0, stream>>>(pval, pidx, out);

  // fine match (reads coarse result from d_out)
  fine_kernel<<<dim3(WCC, HCC, BB), 192, 0, stream>>>(f1f, fkf, na_f, nq_f, out, out + BB*HCC*WCC*2);
}